// Round 4
// baseline (517.615 us; speedup 1.0000x reference)
//
#include <hip/hip_runtime.h>

typedef __attribute__((ext_vector_type(8))) short bf16x8;
typedef __attribute__((ext_vector_type(8))) unsigned short u16x8;
typedef __attribute__((ext_vector_type(4))) unsigned short u16x4;
typedef __attribute__((ext_vector_type(4))) float f32x4;

#define HW      112
#define CH      64
#define PIX_IMG (HW*HW)            // 12544
#define N4TOT   (64*112*112*64/4)  // 12845056 float4s in x
#define NPIX_F  802816.0f          // 64*112*112

// ws layout (floats): [0..64) sum, [64..128) sumsq. (scale/bias now local to
// finalize_prep; only hv + bias_out persist.)
// [256..320) bias_out (= sum_tap,ci b*W).
// byte 1280: hv bf16[64] = bf16(-b/s)  (raw-x halo value -> x_bn == 0)
// byte 4096: W' bf16 [half][tap][qd][co][8]  (36864 ushorts, 73728 B), W' = s*W
// byte 4MB : raw bf16 x [n][h][w][ci]  (102,760,448 B) when ws_size permits
#define WS_HV_BYTE  1280
#define WS_W_BYTE   4096
#define WS_XBF_BYTE (4u<<20)

__device__ __forceinline__ unsigned short f2bf(float f) {
  unsigned u = __float_as_uint(f);
  u += 0x7FFFu + ((u >> 16) & 1u);   // round-to-nearest-even
  return (unsigned short)(u >> 16);
}

// ---------------- kernel 0: zero the stat accumulators ----------------
__global__ void zero_ws(float* __restrict__ ws) {
  ws[threadIdx.x] = 0.0f;   // 128 threads: sum[64], sumsq[64]
}

// ---------------- kernel 1: per-channel sum/sumsq (+ optional raw bf16 x) ----
// nt LOADS only (x is read-once here). Stores stay cached (R2: nt stores
// amplified WRITE_SIZE 323->419 MB; dur tracks bytes at ~3.5 TB/s).
template <bool WRITE_BF>
__global__ __launch_bounds__(256) void stats_kernel(const float* __restrict__ x,
                                                    float* __restrict__ ws,
                                                    unsigned short* __restrict__ xbf) {
  __shared__ float red[128];
  const int tid = threadIdx.x;
  if (tid < 128) red[tid] = 0.0f;
  __syncthreads();

  const f32x4* __restrict__ x4 = (const f32x4*)x;
  f32x4 s = {0.f, 0.f, 0.f, 0.f};
  f32x4 q = {0.f, 0.f, 0.f, 0.f};
  const int stride = gridDim.x * 256;
  #pragma unroll 4
  for (int i = blockIdx.x * 256 + tid; i < N4TOT; i += stride) {
    f32x4 v = __builtin_nontemporal_load(&x4[i]);
    s += v;
    q += v * v;
    if (WRITE_BF) {
      u16x4 o = {f2bf(v[0]), f2bf(v[1]), f2bf(v[2]), f2bf(v[3])};
      *(u16x4*)(xbf + 4 * i) = o;
    }
  }
  // lanes l, l^16, l^32 share the same channel quad -> shuffle pre-reduce
  #pragma unroll
  for (int m = 16; m <= 32; m <<= 1) {
    #pragma unroll
    for (int j = 0; j < 4; ++j) {
      s[j] += __shfl_xor(s[j], m);
      q[j] += __shfl_xor(q[j], m);
    }
  }
  if ((tid & 63) < 16) {
    const int c0 = (tid & 15) * 4;
    #pragma unroll
    for (int j = 0; j < 4; ++j) {
      atomicAdd(&red[c0 + j], s[j]);
      atomicAdd(&red[64 + c0 + j], q[j]);
    }
  }
  __syncthreads();
  if (tid < 128) atomicAdd(&ws[tid], red[tid]);
}

// ------- kernel 2 (merged): scale/bias/halo/bias_out + W' = s*W --------------
// 144 blocks x 256. Every block recomputes per-channel scale locally (cheap:
// 128 floats) and scales its 256-element W' chunk. Block 0 additionally
// writes hv and bias_out.
__global__ __launch_bounds__(256) void finalize_prep(const float* __restrict__ beta,
                                                     const float* __restrict__ k,
                                                     float* __restrict__ ws,
                                                     unsigned short* __restrict__ wsw) {
  __shared__ float scl[64];
  __shared__ float sb[64];
  __shared__ float part[256];
  const int tid = threadIdx.x;
  if (tid < 64) {
    float mean = ws[tid] * (1.0f / NPIX_F);
    float var  = fmaxf(ws[64 + tid] * (1.0f / NPIX_F) - mean * mean, 0.0f);
    float sc = rsqrtf(var + 1e-5f);
    float b  = beta[tid] - mean * sc;
    scl[tid] = sc;
    sb[tid]  = b;
    if (blockIdx.x == 0)
      ((unsigned short*)((char*)ws + WS_HV_BYTE))[tid] = f2bf(-b / sc);
  }
  __syncthreads();

  // W' chunk: oidx decode [half][tap][qd][co][8]
  {
    const int oidx = blockIdx.x * 256 + tid;  // 36864 total
    const int j  = oidx & 7;
    const int co = (oidx >> 3) & 63;
    const int qd = (oidx >> 9) & 3;
    const int t2 = oidx >> 11;          // 0..17
    const int tap = t2 % 9;
    const int h   = t2 / 9;
    const int ci  = h * 32 + qd * 8 + j;
    wsw[oidx] = f2bf(k[(tap * 64 + ci) * 64 + co] * scl[ci]);
  }

  if (blockIdx.x == 0) {
    const int co = tid & 63, pt = tid >> 6;
    float a = 0.f;
    #pragma unroll 8
    for (int t = pt; t < 576; t += 4)          // t = tap*64 + ci
      a = fmaf(sb[t & 63], k[t * 64 + co], a);
    part[tid] = a;
    __syncthreads();
    if (tid < 64)
      ws[256 + tid] = part[tid] + part[64 + tid] + part[128 + tid] + part[192 + tid];
  }
}

// ---------------- kernel 3: 3x3 conv, wave-autonomous staging ----------------
// Block: 448 threads (7 waves) = 4 output rows of one image; wave wv owns
// output cols [16wv, 16wv+16).
// LDS Wd: BOTH halves of W' staged once [half][tap][qd][co][8] = 73,728 B;
//   the ONLY barrier in the kernel is after this stage.
// LDS Xs: PER-WAVE private slice [wv][qd 4][row 6][px 18][8] = 3456 ushorts
//   per wave (6,912 B), 48,384 B total. Waves never share Xs -> X staging and
//   compute need no block barriers; waves free-run and de-phase, so memory
//   stays busy while other waves compute (the 3.5 TB/s plateau was the
//   barrier-synced burst pattern).
// T14 half-1 prefetch: issue half-1 global loads into 7 u16x8 regs right
//   after half-0 staging, compute half 0, then ds_write them -> half-1 HBM
//   latency hides under half-0 MFMA. 1 block/CU (LDS 122,112 B), so the +28
//   transient VGPRs are free (256/wave budget at 2 waves/SIMD).
// Cost: w-halo staged per wave (18 px per 16 produced) -> FETCH +~12%.
template <bool USE_BF>
__global__ __launch_bounds__(448, 2) void conv_kernel(const float* __restrict__ x,
                                                      const unsigned short* __restrict__ xbf,
                                                      const unsigned short* __restrict__ wsw,
                                                      const float* __restrict__ ws,
                                                      float* __restrict__ out) {
  __shared__ unsigned short Xs[7 * 3456];   // 48,384 B
  __shared__ unsigned short Wd[36864];      // 73,728 B
  const int tid = threadIdx.x;
  const int bid = (int)blockIdx.x;
  const int n  = bid / 28;
  const int h0 = (bid % 28) * 4;

  const int lane = tid & 63;
  const int wv   = tid >> 6;    // 0..6 -> out w base = 16*wv
  const int qd   = lane >> 4;
  const int cc   = lane & 15;
  const int wvb  = wv * 16;

  const unsigned short* hv = (const unsigned short*)((const char*)ws + WS_HV_BYTE);
  unsigned short* Xw = &Xs[wv * 3456];

  // acc init = bias_out (covers the +b term for every tap; halo yields 0)
  f32x4 acc[4][4];
  {
    const float* bo = ws + 256;
    #pragma unroll
    for (int mt = 0; mt < 4; ++mt) {
      const f32x4 bv = *(const f32x4*)(bo + mt * 16 + qd * 4);
      #pragma unroll
      for (int r = 0; r < 4; ++r) acc[r][mt] = bv;
    }
  }

  // ---- cooperative Wd stage (both halves); the kernel's only barrier ----
  for (int t = tid; t < 4608; t += 448)
    *(u16x8*)(&Wd[t * 8]) = *(const u16x8*)(wsw + t * 8);
  __syncthreads();

  // element decode for e = kk*64 + lane (e < 432):
  //   o = e&3 (qd plane), r2 = e>>2 (= row*18+px), px = r2%18, row = r2/18
  //   global w = wvb+px-1, g = h0+row-1; LDS off = o*864 + r2*8

  // ---- stage own Xs, half 0 (direct load -> LDS) ----
  {
    u16x8 hv8[4];
    #pragma unroll
    for (int o = 0; o < 4; ++o) hv8[o] = *(const u16x8*)(hv + o * 8);
    #pragma unroll
    for (int kk = 0; kk < 7; ++kk) {
      const int e = kk * 64 + lane;
      if (kk < 6 || lane < 48) {
        const int o = e & 3, r2 = e >> 2;
        const int px = r2 % 18, row = r2 / 18;
        const int w = wvb + px - 1, g = h0 + row - 1;
        u16x8 v;
        if ((unsigned)w < 112u && (unsigned)g < 112u) {
          const int base = ((n * 112 + g) * 112 + w) * 64 + o * 8;
          if (USE_BF) {
            v = *(const u16x8*)(xbf + base);
          } else {
            const float* sp = x + base;
            const f32x4 a = *(const f32x4*)sp;
            const f32x4 b = *(const f32x4*)(sp + 4);
            v = (u16x8){f2bf(a[0]), f2bf(a[1]), f2bf(a[2]), f2bf(a[3]),
                        f2bf(b[0]), f2bf(b[1]), f2bf(b[2]), f2bf(b[3])};
          }
        } else {
          v = hv8[o];
        }
        *(u16x8*)(&Xw[o * 864 + r2 * 8]) = v;
      }
    }
  }

  // ---- T14: issue half-1 loads into regs now; they fly during compute(0) ----
  u16x8 pf[7];
  if (USE_BF) {
    #pragma unroll
    for (int kk = 0; kk < 7; ++kk) {
      const int e = kk * 64 + lane;
      if (kk < 6 || lane < 48) {
        const int o = e & 3, r2 = e >> 2;
        const int px = r2 % 18, row = r2 / 18;
        const int w = wvb + px - 1, g = h0 + row - 1;
        if ((unsigned)w < 112u && (unsigned)g < 112u)
          pf[kk] = *(const u16x8*)(xbf + ((n * 112 + g) * 112 + w) * 64 + 32 + o * 8);
      }
    }
    __builtin_amdgcn_sched_barrier(0);   // pin issue point (don't sink loads)
  }

  // ---- compute one half: 144 MFMA, xb ring-of-4, no barriers ----
  auto compute = [&](int half) {
    const int wb = half * 18432;
    #pragma unroll
    for (int dw = 0; dw < 3; ++dw) {
      bf16x8 xb[4];
      #pragma unroll
      for (int rr = 0; rr < 4; ++rr)
        xb[rr] = *(const bf16x8*)(&Xw[qd * 864 + (rr * 18 + dw + cc) * 8]);
      #pragma unroll
      for (int dh = 0; dh < 3; ++dh) {
        if (dh)   // replace oldest row with row dh+3
          xb[(dh + 3) & 3] =
              *(const bf16x8*)(&Xw[qd * 864 + ((dh + 3) * 18 + dw + cc) * 8]);
        #pragma unroll
        for (int mt = 0; mt < 4; ++mt) {
          const bf16x8 wa = *(const bf16x8*)(
              &Wd[wb + (((dh * 3 + dw) * 4 + qd) * 64 + mt * 16 + cc) * 8]);
          #pragma unroll
          for (int r = 0; r < 4; ++r)
            acc[r][mt] = __builtin_amdgcn_mfma_f32_16x16x32_bf16(wa, xb[(dh + r) & 3],
                                                                 acc[r][mt], 0, 0, 0);
        }
      }
    }
  };

  compute(0);

  // ---- stage own Xs, half 1 (write prefetched regs; wave-local, no barrier) --
  {
    u16x8 hv8[4];
    #pragma unroll
    for (int o = 0; o < 4; ++o) hv8[o] = *(const u16x8*)(hv + 32 + o * 8);
    #pragma unroll
    for (int kk = 0; kk < 7; ++kk) {
      const int e = kk * 64 + lane;
      if (kk < 6 || lane < 48) {
        const int o = e & 3, r2 = e >> 2;
        const int px = r2 % 18, row = r2 / 18;
        const int w = wvb + px - 1, g = h0 + row - 1;
        const bool ok = (unsigned)w < 112u && (unsigned)g < 112u;
        u16x8 v;
        if (USE_BF) {
          v = ok ? pf[kk] : hv8[o];
        } else {
          if (ok) {
            const float* sp = x + ((n * 112 + g) * 112 + w) * 64 + 32 + o * 8;
            const f32x4 a = *(const f32x4*)sp;
            const f32x4 b = *(const f32x4*)(sp + 4);
            v = (u16x8){f2bf(a[0]), f2bf(a[1]), f2bf(a[2]), f2bf(a[3]),
                        f2bf(b[0]), f2bf(b[1]), f2bf(b[2]), f2bf(b[3])};
          } else {
            v = hv8[o];
          }
        }
        *(u16x8*)(&Xw[o * 864 + r2 * 8]) = v;
      }
    }
  }

  compute(1);

  // epilogue: lane holds px col = cc, co rows = mt*16 + qd*4 + 0..3
  #pragma unroll
  for (int r = 0; r < 4; ++r) {
    const int pix = n * PIX_IMG + (h0 + r) * 112 + wvb + cc;
    float* op = out + pix * 64 + qd * 4;
    #pragma unroll
    for (int mt = 0; mt < 4; ++mt)
      *(f32x4*)(op + mt * 16) = acc[r][mt];
  }
}

extern "C" void kernel_launch(void* const* d_in, const int* in_sizes, int n_in,
                              void* d_out, int out_size, void* d_ws, size_t ws_size,
                              hipStream_t stream) {
  const float* x    = (const float*)d_in[0];
  const float* kern = (const float*)d_in[1];
  const float* beta = (const float*)d_in[2];
  float* out = (float*)d_out;
  float* ws  = (float*)d_ws;
  unsigned short* wsw = (unsigned short*)((char*)d_ws + WS_W_BYTE);
  unsigned short* xbf = (unsigned short*)((char*)d_ws + WS_XBF_BYTE);

  const bool use_bf = ws_size >= (size_t)WS_XBF_BYTE + 102760448ull;

  zero_ws<<<1, 128, 0, stream>>>(ws);
  if (use_bf) stats_kernel<true ><<<2048, 256, 0, stream>>>(x, ws, xbf);
  else        stats_kernel<false><<<2048, 256, 0, stream>>>(x, ws, xbf);
  finalize_prep<<<144, 256, 0, stream>>>(beta, kern, ws, wsw);
  if (use_bf) conv_kernel<true ><<<64 * 28, 448, 0, stream>>>(x, xbf, wsw, ws, out);
  else        conv_kernel<false><<<64 * 28, 448, 0, stream>>>(x, xbf, wsw, ws, out);
}